// Round 2
// baseline (464.120 us; speedup 1.0000x reference)
//
#include <hip/hip_runtime.h>
#include <cmath>

#define NB 256   // batch
#define NT 512   // seq len
#define ND 50    // emb dim
#define NH 50    // hidden
#define NC 5     // classes

__device__ __forceinline__ float rcpf(float x) { return __builtin_amdgcn_rcpf(x); }

// ---------------- K1: xp[b,t,:] = W_ih @ emb[x[b,t]] + b_ih + b_hh (permuted layout) ----
__global__ __launch_bounds__(256)
void k1_xproj(const int* __restrict__ x, const int* __restrict__ lengths,
              const float* __restrict__ emb_table,
              const float* __restrict__ W_ih, const float* __restrict__ b_ih,
              const float* __restrict__ b_hh,
              float* __restrict__ xp, int t0, int t1, int tiles, int tcAlloc)
{
    const int b    = blockIdx.x / tiles;
    const int tile = blockIdx.x % tiles;
    const int rt0  = t0 + tile * 32;
    if (rt0 >= t1) return;
    if (rt0 >= lengths[b]) return;            // rows past length are never consumed
    const int nrows = min(32, t1 - rt0);

    __shared__ int xv[32];
    __shared__ __align__(16) float eL[32][52]; // 208B row stride -> float4-aligned

    const int tid = threadIdx.x;

    float w[ND]; float bsum = 0.f;
    if (tid < 200) {
        #pragma unroll
        for (int j = 0; j < ND; ++j) w[j] = W_ih[tid * ND + j];
        bsum = b_ih[tid] + b_hh[tid];
        #pragma unroll
        for (int j = 0; j < ND; ++j) asm volatile("" : "+v"(w[j]));  // pin: no remat
    }
    if (tid < nrows) xv[tid] = x[(size_t)b * NT + rt0 + tid];
    __syncthreads();
    for (int idx = tid; idx < nrows * ND; idx += 256) {
        int row = idx / ND, col = idx - row * ND;
        eL[row][col] = emb_table[(size_t)xv[row] * ND + col];
    }
    __syncthreads();
    if (tid < 200) {
        const int wr = 4 * (tid % NH) + (tid / NH);      // quad-permuted position
        float* xpb = xp + ((size_t)b * tcAlloc + (rt0 - t0)) * 200 + wr;
        for (int row = 0; row < nrows; ++row) {
            const float4* ep = (const float4*)&eL[row][0];
            float a0 = bsum, a1 = 0.f, a2 = 0.f, a3 = 0.f;
            #pragma unroll
            for (int j = 0; j < 12; ++j) {
                float4 e = ep[j];
                a0 = fmaf(e.x, w[4*j+0], a0);
                a1 = fmaf(e.y, w[4*j+1], a1);
                a2 = fmaf(e.z, w[4*j+2], a2);
                a3 = fmaf(e.w, w[4*j+3], a3);
            }
            a0 = fmaf(eL[row][48], w[48], a0);
            a1 = fmaf(eL[row][49], w[49], a1);
            xpb[(size_t)row * 200] = (a0 + a1) + (a2 + a3);
        }
    }
}

// ---------------- K2: sequential LSTM scan (h-projection only) --------------------------
__global__ __launch_bounds__(256, 1)
void k2_scan(const int* __restrict__ lengths, const float* __restrict__ W_hh,
             const float* __restrict__ xp,
             float* __restrict__ stH, float* __restrict__ stC, float* __restrict__ lastH,
             int t0, int t1, int tcAlloc)
{
    const int b = blockIdx.x, tid = threadIdx.x;
    __shared__ __align__(16) float hb[2][52];

    const bool gm = tid < 200;
    const int  q = tid & 3, k = tid >> 2;

    float w[NH]; float cst = 0.f; float scale = 1.f, addc = 0.f;
    if (gm) {
        const int r = q * NH + k;
        #pragma unroll
        for (int j = 0; j < NH; ++j) w[j] = W_hh[r * NH + j];
        #pragma unroll
        for (int j = 0; j < NH; ++j) asm volatile("" : "+v"(w[j]));  // pin: no remat
        if (q == 2) { scale = 2.f; addc = -1.f; }                    // tanh via sigmoid
        cst = (t0 == 0) ? 0.f : stC[b * NH + k];
    }
    if (tid < NH) hb[0][tid] = (t0 == 0) ? 0.f : stH[b * NH + tid];

    const int lastidx = min(lengths[b], NT) - 1;
    const int nsteps  = t1 - t0;
    const float* xpb  = xp + ((size_t)b * tcAlloc) * 200 + tid;

    float x0 = 0.f, x1 = 0.f, x2 = 0.f, hkeep = 0.f;
    if (gm) {
        x0 = xpb[0];
        x1 = (nsteps > 1) ? xpb[200] : 0.f;
        x2 = (nsteps > 2) ? xpb[400] : 0.f;
    }
    __syncthreads();

    int cur = 0;
    for (int s = 0; s < nsteps; ++s) {
        if (gm) {
            const float4* hp = (const float4*)&hb[cur][0];
            float a0 = x0, a1 = 0.f, a2 = 0.f, a3 = 0.f;
            #pragma unroll
            for (int j = 0; j < 12; ++j) {
                float4 h4 = hp[j];
                a0 = fmaf(h4.x, w[4*j+0], a0);
                a1 = fmaf(h4.y, w[4*j+1], a1);
                a2 = fmaf(h4.z, w[4*j+2], a2);
                a3 = fmaf(h4.w, w[4*j+3], a3);
            }
            a2 = fmaf(hb[cur][48], w[48], a2);
            a3 = fmaf(hb[cur][49], w[49], a3);
            float g = (a0 + a1) + (a2 + a3);
            float act = fmaf(rcpf(1.f + __expf(-scale * g)), scale, addc);
            float v1 = __shfl_xor(act, 1);
            float v2 = __shfl_xor(act, 2);
            float v3 = __shfl_xor(v1, 2);
            const bool b0 = q & 1, b1 = q & 2;
            float i_  = b1 ? (b0 ? v3 : v2) : (b0 ? v1 : act);
            float f_  = b1 ? (b0 ? v2 : v3) : (b0 ? act : v1);
            float gt_ = b1 ? (b0 ? v1 : act) : (b0 ? v3 : v2);
            float o_  = b1 ? (b0 ? act : v1) : (b0 ? v2 : v3);
            cst = fmaf(f_, cst, i_ * gt_);
            float th = fmaf(rcpf(1.f + __expf(-2.f * cst)), 2.f, -1.f);
            float h = o_ * th;
            if (q == 0) {
                hb[cur ^ 1][k] = h;
                hkeep = h;
                if (t0 + s == lastidx) lastH[b * NH + k] = h;
            }
            x0 = x1; x1 = x2;
            x2 = (s + 3 < nsteps) ? xpb[(size_t)(s + 3) * 200] : 0.f;
        }
        __syncthreads();
        cur ^= 1;
    }
    if (gm && q == 0) { stH[b * NH + k] = hkeep; stC[b * NH + k] = cst; }
}

// ---------------- K3: pooling + concat + linear ------------------------------------------
__global__ __launch_bounds__(256)
void k3_final(const int* __restrict__ x, const int* __restrict__ lengths,
              const float* __restrict__ emb_table,
              const float* __restrict__ W_lin, const float* __restrict__ b_lin,
              const float* __restrict__ lastH, float* __restrict__ out)
{
    const int b = blockIdx.x, tid = threadIdx.x;
    __shared__ int xv[NT];
    __shared__ float ps[5][52], pm[5][52];
    __shared__ float rep[160];

    for (int i = tid; i < NT; i += 256) xv[i] = x[(size_t)b * NT + i];
    __syncthreads();
    const int g = tid / ND, d = tid - g * ND;
    if (tid < 250) {
        float s = 0.f, m = -INFINITY;
        #pragma unroll 4
        for (int t = g; t < NT; t += 5) {
            float e = emb_table[(size_t)xv[t] * ND + d];
            s += e; m = fmaxf(m, e);
        }
        ps[g][d] = s; pm[g][d] = m;
    }
    __syncthreads();
    if (tid < NH) {
        float s = ps[0][tid] + ps[1][tid] + ps[2][tid] + ps[3][tid] + ps[4][tid];
        float m = fmaxf(fmaxf(fmaxf(pm[0][tid], pm[1][tid]), fmaxf(pm[2][tid], pm[3][tid])), pm[4][tid]);
        rep[tid]          = lastH[b * NH + tid];
        rep[NH + tid]     = s / (float)lengths[b];
        rep[2 * NH + tid] = m;
    }
    __syncthreads();
    if (tid < NC) {
        float acc = b_lin[tid];
        #pragma unroll 5
        for (int j = 0; j < 3 * NH; ++j)
            acc = fmaf(rep[j], W_lin[tid * 3 * NH + j], acc);
        out[(size_t)b * NC + tid] = acc;
    }
}

extern "C" void kernel_launch(void* const* d_in, const int* in_sizes, int n_in,
                              void* d_out, int out_size, void* d_ws, size_t ws_size,
                              hipStream_t stream) {
    const int*   x     = (const int*)d_in[0];
    const int*   len   = (const int*)d_in[1];
    const float* emb   = (const float*)d_in[3];
    const float* W_ih  = (const float*)d_in[4];
    const float* W_hh  = (const float*)d_in[5];
    const float* b_ih  = (const float*)d_in[6];
    const float* b_hh  = (const float*)d_in[7];
    const float* W_lin = (const float*)d_in[8];
    const float* b_lin = (const float*)d_in[9];
    float* outp = (float*)d_out;

    // ws layout: [stH 256*50][stC 256*50][lastH 256*50] ... @160KB: xp[B][tc][200]
    float* stH   = (float*)d_ws;
    float* stC   = stH + NB * NH;
    float* lastH = stC + NB * NH;
    const size_t xpOff = 160 * 1024;
    float* xp = (float*)((char*)d_ws + xpOff);

    size_t avail = (ws_size > xpOff) ? ws_size - xpOff : 0;
    int tc = (int)(avail / ((size_t)NB * 200 * sizeof(float)));
    if (tc > NT) tc = NT;
    if (tc < 1)  tc = 1;   // degenerate fallback: many tiny chunks

    for (int t0 = 0; t0 < NT; t0 += tc) {
        const int t1 = min(NT, t0 + tc);
        const int tiles = (t1 - t0 + 31) / 32;
        hipLaunchKernelGGL(k1_xproj, dim3(NB * tiles), dim3(256), 0, stream,
                           x, len, emb, W_ih, b_ih, b_hh, xp, t0, t1, tiles, tc);
        hipLaunchKernelGGL(k2_scan, dim3(NB), dim3(256), 0, stream,
                           len, W_hh, xp, stH, stC, lastH, t0, t1, tc);
    }
    hipLaunchKernelGGL(k3_final, dim3(NB), dim3(256), 0, stream,
                       x, len, emb, W_lin, b_lin, lastH, outp);
}

// Round 3
// 450.491 us; speedup vs baseline: 1.0303x; 1.0303x over previous
//
#include <hip/hip_runtime.h>
#include <cmath>

#define NB 256   // batch
#define NT 512   // seq len
#define ND 50    // emb dim
#define NH 50    // hidden
#define NC 5     // classes

typedef float f32x16 __attribute__((ext_vector_type(16)));

__device__ __forceinline__ float rcpf(float x) { return __builtin_amdgcn_rcpf(x); }

// DPP quad_perm: xor1 = {1,0,3,2} -> 0xB1 ; xor2 = {2,3,0,1} -> 0x4E
template<int CTRL>
__device__ __forceinline__ float qp(float x) {
    int xi = __float_as_int(x);
    return __int_as_float(__builtin_amdgcn_update_dpp(xi, xi, CTRL, 0xF, 0xF, false));
}

// weight getter: j must be a compile-time constant after unrolling -> folds to static extract
#define WW(j) ((j) < 16 ? wv0[(j)] : (j) < 32 ? wv1[(j)-16] : (j) < 48 ? wv2[(j)-32] : ((j) == 48 ? w48 : w49))

// ---------------- K1: xp[b,t,4u+g] = W_ih[g*50+u] . emb[x[b,t]] + b_ih + b_hh ------------
__global__ __launch_bounds__(256)
void k1_xproj(const int* __restrict__ x, const int* __restrict__ lengths,
              const float* __restrict__ emb_table,
              const float* __restrict__ W_ih, const float* __restrict__ b_ih,
              const float* __restrict__ b_hh,
              float* __restrict__ xp, int t0, int t1, int tiles, int tcAlloc)
{
    const int b    = blockIdx.x / tiles;
    const int tile = blockIdx.x % tiles;
    const int rt0  = t0 + tile * 64;
    if (rt0 >= t1) return;
    if (rt0 >= lengths[b]) return;            // rows past length are never consumed
    const int nrows = min(64, t1 - rt0);

    __shared__ int xv[64];
    __shared__ __align__(16) float eL[64][52]; // 208B row stride, float4-aligned

    const int tid = threadIdx.x;

    f32x16 wv0, wv1, wv2; float w48 = 0.f, w49 = 0.f, bsum = 0.f;
    if (tid < 200) {
        const float* wrow = W_ih + tid * ND;
        #pragma unroll
        for (int j = 0; j < 16; ++j) wv0[j] = wrow[j];
        #pragma unroll
        for (int j = 0; j < 16; ++j) wv1[j] = wrow[16 + j];
        #pragma unroll
        for (int j = 0; j < 16; ++j) wv2[j] = wrow[32 + j];
        w48 = wrow[48]; w49 = wrow[49];
        bsum = b_ih[tid] + b_hh[tid];
    }
    if (tid < nrows) xv[tid] = x[(size_t)b * NT + rt0 + tid];
    __syncthreads();
    for (int idx = tid; idx < nrows * ND; idx += 256) {
        int row = idx / ND, col = idx - row * ND;
        eL[row][col] = emb_table[(size_t)xv[row] * ND + col];
    }
    __syncthreads();
    if (tid < 200) {
        const int wr = 4 * (tid % NH) + (tid / NH);      // quad-permuted position
        float* xpb = xp + ((size_t)b * tcAlloc + (rt0 - t0)) * 200 + wr;
        for (int row = 0; row < nrows; ++row) {
            const float4* ep = (const float4*)&eL[row][0];
            float a0 = bsum, a1 = 0.f, a2 = 0.f, a3 = 0.f;
            #pragma unroll
            for (int j = 0; j < 12; ++j) {
                float4 e = ep[j];
                a0 = fmaf(e.x, WW(4*j+0), a0);
                a1 = fmaf(e.y, WW(4*j+1), a1);
                a2 = fmaf(e.z, WW(4*j+2), a2);
                a3 = fmaf(e.w, WW(4*j+3), a3);
            }
            a0 = fmaf(eL[row][48], w48, a0);
            a1 = fmaf(eL[row][49], w49, a1);
            xpb[(size_t)row * 200] = (a0 + a1) + (a2 + a3);
        }
    }
}

// ---------------- K2: sequential LSTM scan (h-projection only) --------------------------
__global__ __launch_bounds__(256, 1)
void k2_scan(const int* __restrict__ lengths, const float* __restrict__ W_hh,
             const float* __restrict__ xp,
             float* __restrict__ stH, float* __restrict__ stC, float* __restrict__ lastH,
             int t0, int t1, int tcAlloc)
{
    const int b = blockIdx.x, tid = threadIdx.x;
    __shared__ __align__(16) float hb[2][52];

    const bool gm = tid < 200;
    const int  q = tid & 3, k = tid >> 2;

    f32x16 wv0, wv1, wv2; float w48 = 0.f, w49 = 0.f;
    float cst = 0.f, scale = 1.f, addc = 0.f;
    if (gm) {
        const float* wrow = W_hh + (q * NH + k) * NH;
        #pragma unroll
        for (int j = 0; j < 16; ++j) wv0[j] = wrow[j];
        #pragma unroll
        for (int j = 0; j < 16; ++j) wv1[j] = wrow[16 + j];
        #pragma unroll
        for (int j = 0; j < 16; ++j) wv2[j] = wrow[32 + j];
        w48 = wrow[48]; w49 = wrow[49];
        if (q == 2) { scale = 2.f; addc = -1.f; }   // tanh(x) = 2*sigmoid(2x)-1
        cst = (t0 == 0) ? 0.f : stC[b * NH + k];
    }
    if (tid < NH) hb[0][tid] = (t0 == 0) ? 0.f : stH[b * NH + tid];

    const int lastidx = min(lengths[b], NT) - 1;
    const int nsteps  = t1 - t0;
    const float* xpb  = xp + ((size_t)b * tcAlloc) * 200 + tid;

    float x0 = 0.f, x1 = 0.f, x2 = 0.f, x3 = 0.f, hkeep = 0.f;
    if (gm) {
        x0 = xpb[0];
        x1 = (nsteps > 1) ? xpb[200] : 0.f;
        x2 = (nsteps > 2) ? xpb[400] : 0.f;
        x3 = (nsteps > 3) ? xpb[600] : 0.f;
    }
    __syncthreads();

    int cur = 0;
    for (int s = 0; s < nsteps; ++s) {
        if (gm) {
            const float4* hp = (const float4*)&hb[cur][0];
            float a0 = x0, a1 = 0.f, a2 = 0.f, a3 = 0.f;
            #pragma unroll
            for (int j = 0; j < 12; ++j) {
                float4 h4 = hp[j];
                a0 = fmaf(h4.x, WW(4*j+0), a0);
                a1 = fmaf(h4.y, WW(4*j+1), a1);
                a2 = fmaf(h4.z, WW(4*j+2), a2);
                a3 = fmaf(h4.w, WW(4*j+3), a3);
            }
            a2 = fmaf(hb[cur][48], w48, a2);
            a3 = fmaf(hb[cur][49], w49, a3);
            float g = (a0 + a1) + (a2 + a3);
            float act = fmaf(rcpf(1.f + __expf(-scale * g)), scale, addc);
            // quad exchange via DPP (VALU-latency, no LDS round trip)
            float v1 = qp<0xB1>(act);   // xor 1
            float v2 = qp<0x4E>(act);   // xor 2
            float v3 = qp<0x4E>(v1);    // xor 3
            const bool b0 = q & 1, b1 = q & 2;
            float i_  = b1 ? (b0 ? v3 : v2) : (b0 ? v1 : act);
            float f_  = b1 ? (b0 ? v2 : v3) : (b0 ? act : v1);
            float gt_ = b1 ? (b0 ? v1 : act) : (b0 ? v3 : v2);
            float o_  = b1 ? (b0 ? act : v1) : (b0 ? v2 : v3);
            cst = fmaf(f_, cst, i_ * gt_);
            float th = fmaf(rcpf(1.f + __expf(-2.f * cst)), 2.f, -1.f);
            float h = o_ * th;
            if (q == 0) {
                hb[cur ^ 1][k] = h;
                hkeep = h;
                if (t0 + s == lastidx) lastH[b * NH + k] = h;
            }
            x0 = x1; x1 = x2; x2 = x3;
            x3 = (s + 4 < nsteps) ? xpb[(size_t)(s + 4) * 200] : 0.f;
        }
        __syncthreads();
        cur ^= 1;
    }
    if (gm && q == 0) { stH[b * NH + k] = hkeep; stC[b * NH + k] = cst; }
}

// ---------------- K3: pooling + concat + linear ------------------------------------------
__global__ __launch_bounds__(256)
void k3_final(const int* __restrict__ x, const int* __restrict__ lengths,
              const float* __restrict__ emb_table,
              const float* __restrict__ W_lin, const float* __restrict__ b_lin,
              const float* __restrict__ lastH, float* __restrict__ out)
{
    const int b = blockIdx.x, tid = threadIdx.x;
    __shared__ int xv[NT];
    __shared__ float ps[5][52], pm[5][52];
    __shared__ float rep[160];

    for (int i = tid; i < NT; i += 256) xv[i] = x[(size_t)b * NT + i];
    __syncthreads();
    const int g = tid / ND, d = tid - g * ND;
    if (tid < 250) {
        float s = 0.f, m = -INFINITY;
        #pragma unroll 4
        for (int t = g; t < NT; t += 5) {
            float e = emb_table[(size_t)xv[t] * ND + d];
            s += e; m = fmaxf(m, e);
        }
        ps[g][d] = s; pm[g][d] = m;
    }
    __syncthreads();
    if (tid < NH) {
        float s = ps[0][tid] + ps[1][tid] + ps[2][tid] + ps[3][tid] + ps[4][tid];
        float m = fmaxf(fmaxf(fmaxf(pm[0][tid], pm[1][tid]), fmaxf(pm[2][tid], pm[3][tid])), pm[4][tid]);
        rep[tid]          = lastH[b * NH + tid];
        rep[NH + tid]     = s / (float)lengths[b];
        rep[2 * NH + tid] = m;
    }
    __syncthreads();
    if (tid < NC) {
        float acc = b_lin[tid];
        #pragma unroll 5
        for (int j = 0; j < 3 * NH; ++j)
            acc = fmaf(rep[j], W_lin[tid * 3 * NH + j], acc);
        out[(size_t)b * NC + tid] = acc;
    }
}

extern "C" void kernel_launch(void* const* d_in, const int* in_sizes, int n_in,
                              void* d_out, int out_size, void* d_ws, size_t ws_size,
                              hipStream_t stream) {
    const int*   x     = (const int*)d_in[0];
    const int*   len   = (const int*)d_in[1];
    const float* emb   = (const float*)d_in[3];
    const float* W_ih  = (const float*)d_in[4];
    const float* W_hh  = (const float*)d_in[5];
    const float* b_ih  = (const float*)d_in[6];
    const float* b_hh  = (const float*)d_in[7];
    const float* W_lin = (const float*)d_in[8];
    const float* b_lin = (const float*)d_in[9];
    float* outp = (float*)d_out;

    // ws layout: [stH 256*50][stC 256*50][lastH 256*50] ... @160KB: xp[B][tc][200]
    float* stH   = (float*)d_ws;
    float* stC   = stH + NB * NH;
    float* lastH = stC + NB * NH;
    const size_t xpOff = 160 * 1024;
    float* xp = (float*)((char*)d_ws + xpOff);

    size_t avail = (ws_size > xpOff) ? ws_size - xpOff : 0;
    int tc = (int)(avail / ((size_t)NB * 200 * sizeof(float)));
    if (tc > NT) tc = NT;
    if (tc < 1)  tc = 1;

    for (int t0 = 0; t0 < NT; t0 += tc) {
        const int t1 = min(NT, t0 + tc);
        const int tiles = (t1 - t0 + 63) / 64;
        hipLaunchKernelGGL(k1_xproj, dim3(NB * tiles), dim3(256), 0, stream,
                           x, len, emb, W_ih, b_ih, b_hh, xp, t0, t1, tiles, tc);
        hipLaunchKernelGGL(k2_scan, dim3(NB), dim3(256), 0, stream,
                           len, W_hh, xp, stH, stC, lastH, t0, t1, tc);
    }
    hipLaunchKernelGGL(k3_final, dim3(NB), dim3(256), 0, stream,
                       x, len, emb, W_lin, b_lin, lastH, outp);
}

// Round 4
// 323.380 us; speedup vs baseline: 1.4352x; 1.3931x over previous
//
#include <hip/hip_runtime.h>
#include <cmath>

#define NB 256   // batch
#define NT 512   // seq len
#define ND 50    // emb dim
#define NH 50    // hidden
#define NC 5     // classes

typedef float f32x4 __attribute__((ext_vector_type(4)));

__device__ __forceinline__ float rcpf(float x) { return __builtin_amdgcn_rcpf(x); }

// DPP quad_perm: xor1 = {1,0,3,2} -> 0xB1 ; xor2 = {2,3,0,1} -> 0x4E
template<int CTRL>
__device__ __forceinline__ float qp(float x) {
    int xi = __float_as_int(x);
    return __int_as_float(__builtin_amdgcn_update_dpp(xi, xi, CTRL, 0xF, 0xF, false));
}

// asm loads: results are NOT rematerializable -> allocator must keep them in VGPRs
__device__ __forceinline__ void gload4(f32x4& d, const float* p) {
    asm volatile("global_load_dwordx4 %0, %1, off" : "=v"(d) : "v"(p));
}
__device__ __forceinline__ void gload1(float& d, const float* p) {
    asm volatile("global_load_dword %0, %1, off" : "=v"(d) : "v"(p));
}

// ---------------- K0: repack weights into padded/permuted [200][52] rows -----------------
__global__ __launch_bounds__(256)
void k0_prep(const float* __restrict__ W_hh, const float* __restrict__ W_ih,
             float* __restrict__ wsWhh, float* __restrict__ wsWih)
{
    int idx = blockIdx.x * 256 + threadIdx.x;
    if (idx < 200 * 52) {
        int d = idx / 52, c = idx - (idx / 52) * 52;
        int r = (d & 3) * NH + (d >> 2);              // quad-permuted: dest row 4k+q <- src row q*50+k
        wsWhh[idx] = (c < NH) ? W_hh[r * NH + c] : 0.f;
    } else if (idx < 2 * 200 * 52) {
        int j = idx - 200 * 52;
        int d = j / 52, c = j - (j / 52) * 52;
        wsWih[j] = (c < ND) ? W_ih[d * ND + c] : 0.f; // no permute, just pad
    }
}

#define LOADW(i) gload4(w##i, wrow + 4 * (i))
#define DECLW f32x4 w0{},w1{},w2{},w3{},w4{},w5{},w6{},w7{},w8{},w9{},w10{},w11{},w12{}

#define DOT(J, HP) { f32x4 h4 = (HP)[J];                          \
    a0 = fmaf(h4.x, w##J.x, a0); a1 = fmaf(h4.y, w##J.y, a1);     \
    a2 = fmaf(h4.z, w##J.z, a2); a3 = fmaf(h4.w, w##J.w, a3); }
#define DOT13(HP) DOT(0,HP) DOT(1,HP) DOT(2,HP) DOT(3,HP) DOT(4,HP) DOT(5,HP) \
    DOT(6,HP) DOT(7,HP) DOT(8,HP) DOT(9,HP) DOT(10,HP) DOT(11,HP) DOT(12,HP)

// ---------------- K1: xp[b,t,4u+g] = W_ih[g*50+u] . emb[x[b,t]] + b_ih + b_hh ------------
__global__ __launch_bounds__(256)
void k1_xproj(const int* __restrict__ x, const int* __restrict__ lengths,
              const float* __restrict__ emb_table,
              const float* __restrict__ wsWih, const float* __restrict__ b_ih,
              const float* __restrict__ b_hh,
              float* __restrict__ xp, int t0, int t1, int tiles, int tcAlloc)
{
    const int b    = blockIdx.x / tiles;
    const int tile = blockIdx.x % tiles;
    const int rt0  = t0 + tile * 64;
    if (rt0 >= t1) return;
    if (rt0 >= lengths[b]) return;            // rows past length are never consumed
    const int nrows = min(64, t1 - rt0);

    __shared__ int xv[64];
    __shared__ __align__(16) float eL[64][52];

    const int tid = threadIdx.x;

    DECLW; float bsum = 0.f;
    if (tid < 200) {
        const float* wrow = wsWih + tid * 52;
        LOADW(0); LOADW(1); LOADW(2); LOADW(3); LOADW(4); LOADW(5); LOADW(6);
        LOADW(7); LOADW(8); LOADW(9); LOADW(10); LOADW(11); LOADW(12);
        bsum = b_ih[tid] + b_hh[tid];
    }
    if (tid < nrows) xv[tid] = x[(size_t)b * NT + rt0 + tid];
    __syncthreads();
    for (int idx = tid; idx < nrows * 52; idx += 256) {
        int row = idx / 52, col = idx - row * 52;
        eL[row][col] = (col < ND) ? emb_table[(size_t)xv[row] * ND + col] : 0.f;
    }
    asm volatile("s_waitcnt vmcnt(0)" ::: "memory");  // weights resident
    __builtin_amdgcn_sched_barrier(0);
    __syncthreads();
    if (tid < 200) {
        const int wr = 4 * (tid % NH) + (tid / NH);   // quad-permuted position
        float* xpb = xp + ((size_t)b * tcAlloc + (rt0 - t0)) * 200 + wr;
        for (int row = 0; row < nrows; ++row) {
            const f32x4* ep = (const f32x4*)&eL[row][0];
            float a0 = bsum, a1 = 0.f, a2 = 0.f, a3 = 0.f;
            DOT13(ep)
            xpb[(size_t)row * 200] = (a0 + a1) + (a2 + a3);
        }
    }
}

// ---------------- K2: sequential LSTM scan, counted-vmcnt pipeline -----------------------
#define FENCE_BAR                                             \
    asm volatile("s_waitcnt lgkmcnt(0)" ::: "memory");        \
    __builtin_amdgcn_s_barrier();                             \
    asm volatile("" ::: "memory");

#define STEP(XQ, S, CUR)                                                     \
    if (gm) {                                                                \
        asm volatile("s_waitcnt vmcnt(3)" : "+v"(XQ));                       \
        float a0 = XQ, a1 = 0.f, a2 = 0.f, a3 = 0.f;                         \
        gload1(XQ, xpb + (size_t)((S) + 4) * 200);                           \
        const f32x4* hp = (const f32x4*)&hb[CUR][0];                         \
        DOT13(hp)                                                            \
        float g = (a0 + a1) + (a2 + a3);                                     \
        float act = fmaf(rcpf(1.f + __expf(-scale * g)), scale, addc);       \
        float v1 = qp<0xB1>(act);                                            \
        float v2 = qp<0x4E>(act);                                            \
        float v3 = qp<0x4E>(v1);                                             \
        float i_  = b1v ? (b0v ? v3 : v2) : (b0v ? v1 : act);                \
        float f_  = b1v ? (b0v ? v2 : v3) : (b0v ? act : v1);                \
        float gt_ = b1v ? (b0v ? v1 : act) : (b0v ? v3 : v2);                \
        float o_  = b1v ? (b0v ? act : v1) : (b0v ? v2 : v3);                \
        cst = fmaf(f_, cst, i_ * gt_);                                       \
        float th = fmaf(rcpf(1.f + __expf(-2.f * cst)), 2.f, -1.f);          \
        float hv = o_ * th;                                                  \
        if (q == 0) hb[(CUR) ^ 1][k] = hv;                                   \
        hfin = hv;                                                           \
        hkeep = (t0 + (S) == lastidx) ? hv : hkeep;                          \
    }                                                                        \
    FENCE_BAR

__global__ __launch_bounds__(256, 1)
void k2_scan(const int* __restrict__ lengths, const float* __restrict__ wsWhh,
             const float* __restrict__ xp,
             float* __restrict__ stH, float* __restrict__ stC, float* __restrict__ lastH,
             int t0, int t1, int tcAlloc)
{
    const int b = blockIdx.x, tid = threadIdx.x;
    __shared__ __align__(16) float hb[2][52];

    const bool gm = tid < 200;
    const int  q = tid & 3, k = tid >> 2;
    const bool b0v = q & 1, b1v = q & 2;
    const int  nsteps = t1 - t0;
    const float* xpb = xp + ((size_t)b * tcAlloc) * 200 + tid;

    // ---- phase A: all compiler-visible global loads, completed & laundered ----
    int lastidx = min(lengths[b], NT) - 1;
    float cst = 0.f;
    if (gm && t0 != 0) cst = stC[b * NH + k];
    if (tid < 52) {
        hb[0][tid] = (t0 == 0 || tid >= NH) ? 0.f : stH[b * NH + tid];
        hb[1][tid] = 0.f;
    }
    asm volatile("" : "+v"(lastidx), "+v"(cst));  // cut deps: no compiler vmcnt in the loop

    // ---- phase B: asm prefetches (invisible to compiler's waitcnt tracking) ----
    DECLW;
    float xqa = 0.f, xqb = 0.f, xqc = 0.f, xqd = 0.f;
    float scale = 1.f, addc = 0.f, hkeep = 0.f, hfin = 0.f;
    if (gm) {
        const float* wrow = wsWhh + tid * 52;
        LOADW(0); LOADW(1); LOADW(2); LOADW(3); LOADW(4); LOADW(5); LOADW(6);
        LOADW(7); LOADW(8); LOADW(9); LOADW(10); LOADW(11); LOADW(12);
        gload1(xqa, xpb + 0);
        gload1(xqb, xpb + 200);
        gload1(xqc, xpb + 400);
        gload1(xqd, xpb + 600);
        asm volatile("s_waitcnt vmcnt(4)" ::: "memory");  // weights done, 4 xp in flight
        __builtin_amdgcn_sched_barrier(0);
        if (q == 2) { scale = 2.f; addc = -1.f; }         // tanh(x) = 2*sigmoid(2x)-1
    }
    FENCE_BAR

    // ---- main loop: 4 steps/iter, vmcnt never drained below 3 ----
    for (int s4 = 0; s4 < nsteps; s4 += 4) {
        STEP(xqa, s4 + 0, 0)
        STEP(xqb, s4 + 1, 1)
        STEP(xqc, s4 + 2, 0)
        STEP(xqd, s4 + 3, 1)
    }

    if (gm && q == 0) {
        stH[b * NH + k] = hfin;
        stC[b * NH + k] = cst;
        if (lastidx >= t0 && lastidx < t1) lastH[b * NH + k] = hkeep;
    }
}

// ---------------- K3: pooling + concat + linear ------------------------------------------
__global__ __launch_bounds__(256)
void k3_final(const int* __restrict__ x, const int* __restrict__ lengths,
              const float* __restrict__ emb_table,
              const float* __restrict__ W_lin, const float* __restrict__ b_lin,
              const float* __restrict__ lastH, float* __restrict__ out)
{
    const int b = blockIdx.x, tid = threadIdx.x;
    __shared__ int xv[NT];
    __shared__ float ps[5][52], pm[5][52];
    __shared__ float rep[160];

    for (int i = tid; i < NT; i += 256) xv[i] = x[(size_t)b * NT + i];
    __syncthreads();
    const int g = tid / ND, d = tid - g * ND;
    if (tid < 250) {
        float s = 0.f, m = -INFINITY;
        #pragma unroll 4
        for (int t = g; t < NT; t += 5) {
            float e = emb_table[(size_t)xv[t] * ND + d];
            s += e; m = fmaxf(m, e);
        }
        ps[g][d] = s; pm[g][d] = m;
    }
    __syncthreads();
    if (tid < NH) {
        float s = ps[0][tid] + ps[1][tid] + ps[2][tid] + ps[3][tid] + ps[4][tid];
        float m = fmaxf(fmaxf(fmaxf(pm[0][tid], pm[1][tid]), fmaxf(pm[2][tid], pm[3][tid])), pm[4][tid]);
        rep[tid]          = lastH[b * NH + tid];
        rep[NH + tid]     = s / (float)lengths[b];
        rep[2 * NH + tid] = m;
    }
    __syncthreads();
    if (tid < NC) {
        float acc = b_lin[tid];
        #pragma unroll 5
        for (int j = 0; j < 3 * NH; ++j)
            acc = fmaf(rep[j], W_lin[tid * 3 * NH + j], acc);
        out[(size_t)b * NC + tid] = acc;
    }
}

extern "C" void kernel_launch(void* const* d_in, const int* in_sizes, int n_in,
                              void* d_out, int out_size, void* d_ws, size_t ws_size,
                              hipStream_t stream) {
    const int*   x     = (const int*)d_in[0];
    const int*   len   = (const int*)d_in[1];
    const float* emb   = (const float*)d_in[3];
    const float* W_ih  = (const float*)d_in[4];
    const float* W_hh  = (const float*)d_in[5];
    const float* b_ih  = (const float*)d_in[6];
    const float* b_hh  = (const float*)d_in[7];
    const float* W_lin = (const float*)d_in[8];
    const float* b_lin = (const float*)d_in[9];
    float* outp = (float*)d_out;

    // ws layout: [stH][stC][lastH] | @160KB: wsWhh[200*52], wsWih[200*52] | @256KB: xp (+8KB slack)
    float* stH   = (float*)d_ws;
    float* stC   = stH + NB * NH;
    float* lastH = stC + NB * NH;
    float* wsWhh = (float*)((char*)d_ws + 160 * 1024);
    float* wsWih = wsWhh + 200 * 52;
    const size_t xpOff = 256 * 1024;
    float* xp = (float*)((char*)d_ws + xpOff);

    size_t avail = (ws_size > xpOff + 8192) ? ws_size - xpOff - 8192 : 0;
    int tc = (int)(avail / ((size_t)NB * 200 * sizeof(float)));
    tc &= ~3;                 // multiple of 4 -> every chunk's nsteps is a multiple of 4
    if (tc > NT) tc = NT;
    if (tc < 4)  tc = 4;

    hipLaunchKernelGGL(k0_prep, dim3(82), dim3(256), 0, stream, W_hh, W_ih, wsWhh, wsWih);

    for (int t0 = 0; t0 < NT; t0 += tc) {
        const int t1 = min(NT, t0 + tc);
        const int tiles = (t1 - t0 + 63) / 64;
        hipLaunchKernelGGL(k1_xproj, dim3(NB * tiles), dim3(256), 0, stream,
                           x, len, emb, wsWih, b_ih, b_hh, xp, t0, t1, tiles, tc);
        hipLaunchKernelGGL(k2_scan, dim3(NB), dim3(256), 0, stream,
                           len, wsWhh, xp, stH, stC, lastH, t0, t1, tc);
    }
    hipLaunchKernelGGL(k3_final, dim3(NB), dim3(256), 0, stream,
                       x, len, emb, W_lin, b_lin, lastH, outp);
}

// Round 5
// 310.875 us; speedup vs baseline: 1.4929x; 1.0402x over previous
//
#include <hip/hip_runtime.h>
#include <cmath>

#define NB 256   // batch
#define NT 512   // seq len
#define ND 50    // emb dim
#define NH 50    // hidden
#define NC 5     // classes

typedef float f32x4 __attribute__((ext_vector_type(4)));

__device__ __forceinline__ float rcpf(float x) { return __builtin_amdgcn_rcpf(x); }

// DPP quad_perm: xor1 = {1,0,3,2} -> 0xB1 ; xor2 = {2,3,0,1} -> 0x4E
template<int CTRL>
__device__ __forceinline__ float qp(float x) {
    int xi = __float_as_int(x);
    return __int_as_float(__builtin_amdgcn_update_dpp(xi, xi, CTRL, 0xF, 0xF, false));
}
// cross-lane xor-4 within 32-lane group (BitMode: xor=4, and=0x1F)
__device__ __forceinline__ float swz4(float x) {
    return __int_as_float(__builtin_amdgcn_ds_swizzle(__float_as_int(x), 0x101F));
}

// asm loads: results are NOT rematerializable -> allocator must keep them in VGPRs
__device__ __forceinline__ void gload4(f32x4& d, const float* p) {
    asm volatile("global_load_dwordx4 %0, %1, off" : "=v"(d) : "v"(p));
}
__device__ __forceinline__ void gload1(float& d, const float* p) {
    asm volatile("global_load_dword %0, %1, off" : "=v"(d) : "v"(p));
}

// ---------------- K0: repack weights ------------------------------------------------------
// wsWih  [200][52]: W_ih row tid, zero-padded (consumed by k1, unchanged from round 4)
// wsWhh2 [400][28]: interleaved-split W_hh rows for k2's pair-split lanes.
//   lane: k=lane>>3, h_=(lane>>2)&1, q=lane&3, src row r=q*50+k.
//   word j<24: W_hh[r][2j+h_] ; word 24: W_hh[r][48+h_] ; words 25..27: 0
__global__ __launch_bounds__(256)
void k0_prep(const float* __restrict__ W_hh, const float* __restrict__ W_ih,
             float* __restrict__ wsWih, float* __restrict__ wsWhh2)
{
    int idx = blockIdx.x * 256 + threadIdx.x;
    if (idx < 200 * 52) {
        int d = idx / 52, c = idx - (idx / 52) * 52;
        wsWih[idx] = (c < ND) ? W_ih[d * ND + c] : 0.f;
    } else if (idx < 200 * 52 + 400 * 28) {
        int j0 = idx - 200 * 52;
        int lane = j0 / 28, j = j0 - (j0 / 28) * 28;
        int k = lane >> 3, h_ = (lane >> 2) & 1, q = lane & 3;
        int r = q * NH + k;
        float v = 0.f;
        if (j < 24)       v = W_hh[r * NH + 2 * j + h_];
        else if (j == 24) v = W_hh[r * NH + 48 + h_];
        wsWhh2[j0] = v;
    }
}

#define LOADW13(wrow) f32x4 w0{},w1{},w2{},w3{},w4{},w5{},w6{},w7{},w8{},w9{},w10{},w11{},w12{}; \
    gload4(w0,(wrow)+0); gload4(w1,(wrow)+4); gload4(w2,(wrow)+8); gload4(w3,(wrow)+12); \
    gload4(w4,(wrow)+16); gload4(w5,(wrow)+20); gload4(w6,(wrow)+24); gload4(w7,(wrow)+28); \
    gload4(w8,(wrow)+32); gload4(w9,(wrow)+36); gload4(w10,(wrow)+40); gload4(w11,(wrow)+44); \
    gload4(w12,(wrow)+48);

#define DOT(J, HP) { f32x4 h4 = (HP)[J];                          \
    a0 = fmaf(h4.x, w##J.x, a0); a1 = fmaf(h4.y, w##J.y, a1);     \
    a2 = fmaf(h4.z, w##J.z, a2); a3 = fmaf(h4.w, w##J.w, a3); }
#define DOT13(HP) DOT(0,HP) DOT(1,HP) DOT(2,HP) DOT(3,HP) DOT(4,HP) DOT(5,HP) \
    DOT(6,HP) DOT(7,HP) DOT(8,HP) DOT(9,HP) DOT(10,HP) DOT(11,HP) DOT(12,HP)

// ---------------- K1: xp[b,t,4u+g] = W_ih[g*50+u] . emb[x[b,t]] + b_ih + b_hh ------------
// (unchanged from round 4 — proven; optimize later if it becomes the top dispatch)
__global__ __launch_bounds__(256)
void k1_xproj(const int* __restrict__ x, const int* __restrict__ lengths,
              const float* __restrict__ emb_table,
              const float* __restrict__ wsWih, const float* __restrict__ b_ih,
              const float* __restrict__ b_hh,
              float* __restrict__ xp, int t0, int t1, int tiles, int tcAlloc)
{
    const int b    = blockIdx.x / tiles;
    const int tile = blockIdx.x % tiles;
    const int rt0  = t0 + tile * 64;
    if (rt0 >= t1) return;
    if (rt0 >= lengths[b]) return;            // rows past length are never consumed
    const int nrows = min(64, t1 - rt0);

    __shared__ int xv[64];
    __shared__ __align__(16) float eL[64][52];

    const int tid = threadIdx.x;

    float bsum = 0.f;
    const float* wrow = wsWih + tid * 52;
    LOADW13(wrow)
    if (tid < 200) bsum = b_ih[tid] + b_hh[tid];
    if (tid < nrows) xv[tid] = x[(size_t)b * NT + rt0 + tid];
    __syncthreads();
    for (int idx = tid; idx < nrows * 52; idx += 256) {
        int row = idx / 52, col = idx - row * 52;
        eL[row][col] = (col < ND) ? emb_table[(size_t)xv[row] * ND + col] : 0.f;
    }
    asm volatile("s_waitcnt vmcnt(0)" ::: "memory");  // weights resident
    __builtin_amdgcn_sched_barrier(0);
    __syncthreads();
    if (tid < 200) {
        const int wr = 4 * (tid % NH) + (tid / NH);   // quad-permuted position
        float* xpb = xp + ((size_t)b * tcAlloc + (rt0 - t0)) * 200 + wr;
        for (int row = 0; row < nrows; ++row) {
            const f32x4* ep = (const f32x4*)&eL[row][0];
            float a0 = bsum, a1 = 0.f, a2 = 0.f, a3 = 0.f;
            DOT13(ep)
            xpb[(size_t)row * 200] = (a0 + a1) + (a2 + a3);
        }
    }
}

// ---------------- K2: sequential LSTM scan, pair-split + LDS xp ring ---------------------
#define FENCE_BAR                                             \
    asm volatile("s_waitcnt lgkmcnt(0)" ::: "memory");        \
    __builtin_amdgcn_s_barrier();                             \
    asm volatile("" ::: "memory");

__global__ __launch_bounds__(512, 1)
void k2_scan(const int* __restrict__ lengths, const float* __restrict__ wsWhh2,
             const float* __restrict__ xp,
             float* __restrict__ stH, float* __restrict__ stC, float* __restrict__ lastH,
             int t0, int t1, int tcAlloc)
{
    const int b = blockIdx.x, tid = threadIdx.x;
    __shared__ __align__(16) float hbX[2][2][28];   // [cur][parity][unit/2] (+pads)
    __shared__ __align__(16) float ring[4][256];    // xp ring, 4 steps deep

    const bool gm = tid < 400;                 // compute lanes
    const bool st = tid >= 448;                // stager wave (wave 7)
    const int  k  = tid >> 3;                  // hidden unit
    const int  h_ = (tid >> 2) & 1;            // half: 0=even weights, 1=odd
    const int  q  = tid & 3;                   // gate 0=i 1=f 2=g 3=o
    const bool b0v = q & 1, b1v = q & 2;
    const int  nsteps = t1 - t0;

    // ---- init (compiler-visible loads; completed before loop) ----
    int lastidx = min(lengths[b], NT) - 1;
    float cst = 0.f;
    if (gm) cst = (t0 == 0) ? 0.f : stC[b * NH + k];
    if (tid < NH) hbX[0][tid & 1][tid >> 1] = (t0 == 0) ? 0.f : stH[b * NH + tid];

    // ---- weights: 6 f32x4 + tail (25 floats/lane), asm-pinned ----
    f32x4 P0{}, P1{}, P2{}, P3{}, P4{}, P5{}; float wtail = 0.f;
    float scale = 1.f, addc = 0.f, hkeep = 0.f, hfin = 0.f;
    if (gm) {
        const float* wr_ = wsWhh2 + tid * 28;
        gload4(P0, wr_ + 0);  gload4(P1, wr_ + 4);  gload4(P2, wr_ + 8);
        gload4(P3, wr_ + 12); gload4(P4, wr_ + 16); gload4(P5, wr_ + 20);
        gload1(wtail, wr_ + 24);
        asm volatile("s_waitcnt vmcnt(0)" ::: "memory");
        if (q == 2) { scale = 2.f; addc = -1.f; }    // tanh(x) = 2*sigmoid(2x)-1
    }

    // ---- stager prologue: 4-deep pipeline, slot 0 published before first barrier ----
    const float* xpb = xp + (size_t)b * tcAlloc * 200;
    const int sl = tid - 448;
    f32x4 p1{}, p2{}, p3{};
    if (st) {
        f32x4 p0 = *(const f32x4*)(xpb + 0 * 200 + 4 * sl);
        p1 = *(const f32x4*)(xpb + 1 * 200 + 4 * sl);
        p2 = *(const f32x4*)(xpb + 2 * 200 + 4 * sl);
        p3 = *(const f32x4*)(xpb + 3 * 200 + 4 * sl);
        *(f32x4*)&ring[0][4 * sl] = p0;              // compiler waits p0 only
    }
    FENCE_BAR

    // ---- main loop: compute waves have ZERO VMEM; stager waits are compiler-counted ----
    for (int s = 0; s < nsteps; ++s) {
        if (gm) {
            const float* hp = &hbX[s & 1][h_][0];
            const f32x4* hq = (const f32x4*)hp;
            f32x4 h0 = hq[0], h1 = hq[1], h2 = hq[2], h3 = hq[3], h4 = hq[4], h5 = hq[5];
            float htail = hp[24];
            float xq = ring[s & 3][(k << 2) | q];
            float acc0 = h_ ? 0.f : xq;              // seeds a0 (even) / a1 (odd) exactly
            float acc1 = 0.f;
            acc0 = fmaf(h0.x, P0.x, acc0); acc1 = fmaf(h0.y, P0.y, acc1);
            acc0 = fmaf(h0.z, P0.z, acc0); acc1 = fmaf(h0.w, P0.w, acc1);
            acc0 = fmaf(h1.x, P1.x, acc0); acc1 = fmaf(h1.y, P1.y, acc1);
            acc0 = fmaf(h1.z, P1.z, acc0); acc1 = fmaf(h1.w, P1.w, acc1);
            acc0 = fmaf(h2.x, P2.x, acc0); acc1 = fmaf(h2.y, P2.y, acc1);
            acc0 = fmaf(h2.z, P2.z, acc0); acc1 = fmaf(h2.w, P2.w, acc1);
            acc0 = fmaf(h3.x, P3.x, acc0); acc1 = fmaf(h3.y, P3.y, acc1);
            acc0 = fmaf(h3.z, P3.z, acc0); acc1 = fmaf(h3.w, P3.w, acc1);
            acc0 = fmaf(h4.x, P4.x, acc0); acc1 = fmaf(h4.y, P4.y, acc1);
            acc0 = fmaf(h4.z, P4.z, acc0); acc1 = fmaf(h4.w, P4.w, acc1);
            acc0 = fmaf(h5.x, P5.x, acc0); acc1 = fmaf(h5.y, P5.y, acc1);
            acc0 = fmaf(h5.z, P5.z, acc0); acc1 = fmaf(h5.w, P5.w, acc1);
            acc1 = fmaf(htail, wtail, acc1);         // h48*w48 -> a2 / h49*w49 -> a3
            // recombine halves: u=a0+a1, v=a2+a3, g=u+v  (bitwise == rounds 1-3 order)
            float u = acc0 + swz4(acc0);
            float v = acc1 + swz4(acc1);
            float g = u + v;
            float act = fmaf(rcpf(1.f + __expf(-scale * g)), scale, addc);
            // gate quad-exchange via DPP
            float v1 = qp<0xB1>(act);
            float v2 = qp<0x4E>(act);
            float v3 = qp<0x4E>(v1);
            float i_  = b1v ? (b0v ? v3 : v2) : (b0v ? v1 : act);
            float f_  = b1v ? (b0v ? v2 : v3) : (b0v ? act : v1);
            float gt_ = b1v ? (b0v ? v1 : act) : (b0v ? v3 : v2);
            float o_  = b1v ? (b0v ? act : v1) : (b0v ? v2 : v3);
            cst = fmaf(f_, cst, i_ * gt_);
            float th = fmaf(rcpf(1.f + __expf(-2.f * cst)), 2.f, -1.f);
            float hv = o_ * th;
            if ((tid & 7) == 0) hbX[(s & 1) ^ 1][k & 1][k >> 1] = hv;
            hfin = hv;
            hkeep = (t0 + s == lastidx) ? hv : hkeep;
        }
        if (st) {
            *(f32x4*)&ring[(s + 1) & 3][4 * sl] = p1;                      // publish t=s+1
            f32x4 pn = *(const f32x4*)(xpb + (size_t)(s + 4) * 200 + 4 * sl); // fetch t=s+4
            p1 = p2; p2 = p3; p3 = pn;
        }
        FENCE_BAR
    }

    if (gm && (tid & 7) == 0) {
        stH[b * NH + k] = hfin;
        stC[b * NH + k] = cst;
        if (lastidx >= t0 && lastidx < t1) lastH[b * NH + k] = hkeep;
    }
}

// ---------------- K3: pooling + concat + linear (unchanged) ------------------------------
__global__ __launch_bounds__(256)
void k3_final(const int* __restrict__ x, const int* __restrict__ lengths,
              const float* __restrict__ emb_table,
              const float* __restrict__ W_lin, const float* __restrict__ b_lin,
              const float* __restrict__ lastH, float* __restrict__ out)
{
    const int b = blockIdx.x, tid = threadIdx.x;
    __shared__ int xv[NT];
    __shared__ float ps[5][52], pm[5][52];
    __shared__ float rep[160];

    for (int i = tid; i < NT; i += 256) xv[i] = x[(size_t)b * NT + i];
    __syncthreads();
    const int g = tid / ND, d = tid - g * ND;
    if (tid < 250) {
        float s = 0.f, m = -INFINITY;
        #pragma unroll 4
        for (int t = g; t < NT; t += 5) {
            float e = emb_table[(size_t)xv[t] * ND + d];
            s += e; m = fmaxf(m, e);
        }
        ps[g][d] = s; pm[g][d] = m;
    }
    __syncthreads();
    if (tid < NH) {
        float s = ps[0][tid] + ps[1][tid] + ps[2][tid] + ps[3][tid] + ps[4][tid];
        float m = fmaxf(fmaxf(fmaxf(pm[0][tid], pm[1][tid]), fmaxf(pm[2][tid], pm[3][tid])), pm[4][tid]);
        rep[tid]          = lastH[b * NH + tid];
        rep[NH + tid]     = s / (float)lengths[b];
        rep[2 * NH + tid] = m;
    }
    __syncthreads();
    if (tid < NC) {
        float acc = b_lin[tid];
        #pragma unroll 5
        for (int j = 0; j < 3 * NH; ++j)
            acc = fmaf(rep[j], W_lin[tid * 3 * NH + j], acc);
        out[(size_t)b * NC + tid] = acc;
    }
}

extern "C" void kernel_launch(void* const* d_in, const int* in_sizes, int n_in,
                              void* d_out, int out_size, void* d_ws, size_t ws_size,
                              hipStream_t stream) {
    const int*   x     = (const int*)d_in[0];
    const int*   len   = (const int*)d_in[1];
    const float* emb   = (const float*)d_in[3];
    const float* W_ih  = (const float*)d_in[4];
    const float* W_hh  = (const float*)d_in[5];
    const float* b_ih  = (const float*)d_in[6];
    const float* b_hh  = (const float*)d_in[7];
    const float* W_lin = (const float*)d_in[8];
    const float* b_lin = (const float*)d_in[9];
    float* outp = (float*)d_out;

    // ws layout: [stH][stC][lastH] | @160KB: wsWih[200*52], wsWhh2[400*28] | @256KB: xp (+8KB slack)
    float* stH    = (float*)d_ws;
    float* stC    = stH + NB * NH;
    float* lastH  = stC + NB * NH;
    float* wsWih  = (float*)((char*)d_ws + 160 * 1024);
    float* wsWhh2 = wsWih + 200 * 52;
    const size_t xpOff = 256 * 1024;
    float* xp = (float*)((char*)d_ws + xpOff);

    size_t avail = (ws_size > xpOff + 8192) ? ws_size - xpOff - 8192 : 0;
    int tc = (int)(avail / ((size_t)NB * 200 * sizeof(float)));
    tc &= ~3;
    if (tc > NT) tc = NT;
    if (tc < 4)  tc = 4;

    hipLaunchKernelGGL(k0_prep, dim3(85), dim3(256), 0, stream, W_hh, W_ih, wsWih, wsWhh2);

    for (int t0 = 0; t0 < NT; t0 += tc) {
        const int t1 = min(NT, t0 + tc);
        const int tiles = (t1 - t0 + 63) / 64;
        hipLaunchKernelGGL(k1_xproj, dim3(NB * tiles), dim3(256), 0, stream,
                           x, len, emb, wsWih, b_ih, b_hh, xp, t0, t1, tiles, tc);
        hipLaunchKernelGGL(k2_scan, dim3(NB), dim3(512), 0, stream,
                           len, wsWhh2, xp, stH, stC, lastH, t0, t1, tc);
    }
    hipLaunchKernelGGL(k3_final, dim3(NB), dim3(256), 0, stream,
                       x, len, emb, W_lin, b_lin, lastH, outp);
}

// Round 7
// 308.618 us; speedup vs baseline: 1.5039x; 1.0073x over previous
//
#include <hip/hip_runtime.h>
#include <cmath>

#define NB 256   // batch
#define NT 512   // seq len
#define ND 50    // emb dim
#define NH 50    // hidden
#define NC 5     // classes

typedef float f32x4 __attribute__((ext_vector_type(4)));
typedef float f32x2 __attribute__((ext_vector_type(2)));

__device__ __forceinline__ float rcpf(float x) { return __builtin_amdgcn_rcpf(x); }

// DPP quad_perm: xor1 = {1,0,3,2} -> 0xB1 ; xor2 = {2,3,0,1} -> 0x4E
template<int CTRL>
__device__ __forceinline__ float qp(float x) {
    int xi = __float_as_int(x);
    return __int_as_float(__builtin_amdgcn_update_dpp(xi, xi, CTRL, 0xF, 0xF, false));
}
// cross-lane xor-4 within 32-lane group (BitMode: xor=4, and=0x1F)
__device__ __forceinline__ float swz4(float x) {
    return __int_as_float(__builtin_amdgcn_ds_swizzle(__float_as_int(x), 0x101F));
}

// asm loads: results are NOT rematerializable -> allocator must keep them in VGPRs
__device__ __forceinline__ void gload4(f32x4& d, const float* p) {
    asm volatile("global_load_dwordx4 %0, %1, off" : "=v"(d) : "v"(p));
}
__device__ __forceinline__ void gload2(f32x2& d, const float* p) {
    asm volatile("global_load_dwordx2 %0, %1, off" : "=v"(d) : "v"(p));
}

// ---------------- K0: repack weights ------------------------------------------------------
// wsWih [200][52]: W_ih row tid, zero-padded (k1, unchanged — proven)
// wsW2  [400][28]: k2 4-phase lane layout. lane = 8k+4h+p (unit k, gate-pair h, phase p).
//   word 2m+gb (m=0..11, gb=0..1): gate=2h+gb, j=4m+p (<=47): W_hh[(gate*50+k)*50+j]
//   word 24 (wtE): p==2 -> W_hh[gateE][48], p==3 -> W_hh[gateE][49], else 0
//   word 25 (wtO): same for odd gate. words 26,27: 0.
__global__ __launch_bounds__(256)
void k0_prep(const float* __restrict__ W_hh, const float* __restrict__ W_ih,
             float* __restrict__ wsWih, float* __restrict__ wsW2)
{
    int idx = blockIdx.x * 256 + threadIdx.x;
    if (idx < 200 * 52) {
        int d = idx / 52, c = idx - (idx / 52) * 52;
        wsWih[idx] = (c < ND) ? W_ih[d * ND + c] : 0.f;
    } else if (idx < 200 * 52 + 400 * 28) {
        int j0 = idx - 200 * 52;
        int lane = j0 / 28, w = j0 - (j0 / 28) * 28;
        int k = lane >> 3, h2 = (lane >> 2) & 1, p = lane & 3;
        float v = 0.f;
        if (w < 24) {
            int m = w >> 1, gb = w & 1;
            int gate = 2 * h2 + gb;
            int j = 4 * m + p;                       // <= 47, always valid
            v = W_hh[(gate * NH + k) * NH + j];
        } else if (w == 24 || w == 25) {
            int gate = 2 * h2 + (w - 24);
            if (p == 2)      v = W_hh[(gate * NH + k) * NH + 48];
            else if (p == 3) v = W_hh[(gate * NH + k) * NH + 49];
        }
        wsW2[j0] = v;
    }
}

#define DOTI(J, HP) { f32x4 h4 = (HP)[J];                          \
    a0 = fmaf(h4.x, w##J.x, a0); a1 = fmaf(h4.y, w##J.y, a1);     \
    a2 = fmaf(h4.z, w##J.z, a2); a3 = fmaf(h4.w, w##J.w, a3); }
#define DOTI13(HP) DOTI(0,HP) DOTI(1,HP) DOTI(2,HP) DOTI(3,HP) DOTI(4,HP) DOTI(5,HP) \
    DOTI(6,HP) DOTI(7,HP) DOTI(8,HP) DOTI(9,HP) DOTI(10,HP) DOTI(11,HP) DOTI(12,HP)

// ---------------- K1: xp[b,t,4u+g] = W_ih[g*50+u] . emb[x[b,t]] + b_ih + b_hh ------------
// (verbatim round-5 — proven)
__global__ __launch_bounds__(256)
void k1_xproj(const int* __restrict__ x, const int* __restrict__ lengths,
              const float* __restrict__ emb_table,
              const float* __restrict__ wsWih, const float* __restrict__ b_ih,
              const float* __restrict__ b_hh,
              float* __restrict__ xp, int t0, int t1, int tiles, int tcAlloc)
{
    const int b    = blockIdx.x / tiles;
    const int tile = blockIdx.x % tiles;
    const int rt0  = t0 + tile * 64;
    if (rt0 >= t1) return;
    if (rt0 >= lengths[b]) return;            // rows past length are never consumed
    const int nrows = min(64, t1 - rt0);

    __shared__ int xv[64];
    __shared__ __align__(16) float eL[64][52];

    const int tid = threadIdx.x;

    float bsum = 0.f;
    const float* wrow = wsWih + tid * 52;
    f32x4 w0{},w1{},w2{},w3{},w4{},w5{},w6{},w7{},w8{},w9{},w10{},w11{},w12{};
    gload4(w0,wrow+0); gload4(w1,wrow+4); gload4(w2,wrow+8); gload4(w3,wrow+12);
    gload4(w4,wrow+16); gload4(w5,wrow+20); gload4(w6,wrow+24); gload4(w7,wrow+28);
    gload4(w8,wrow+32); gload4(w9,wrow+36); gload4(w10,wrow+40); gload4(w11,wrow+44);
    gload4(w12,wrow+48);
    if (tid < 200) bsum = b_ih[tid] + b_hh[tid];
    if (tid < nrows) xv[tid] = x[(size_t)b * NT + rt0 + tid];
    __syncthreads();
    for (int idx = tid; idx < nrows * 52; idx += 256) {
        int row = idx / 52, col = idx - row * 52;
        eL[row][col] = (col < ND) ? emb_table[(size_t)xv[row] * ND + col] : 0.f;
    }
    asm volatile("s_waitcnt vmcnt(0)" ::: "memory");  // weights resident
    __builtin_amdgcn_sched_barrier(0);
    __syncthreads();
    if (tid < 200) {
        const int wr = 4 * (tid % NH) + (tid / NH);   // quad-permuted position
        float* xpb = xp + ((size_t)b * tcAlloc + (rt0 - t0)) * 200 + wr;
        for (int row = 0; row < nrows; ++row) {
            const f32x4* ep = (const f32x4*)&eL[row][0];
            float a0 = bsum, a1 = 0.f, a2 = 0.f, a3 = 0.f;
            DOTI13(ep)
            xpb[(size_t)row * 200] = (a0 + a1) + (a2 + a3);
        }
    }
}

// ---------------- K2: scan — R5 skeleton (stager+ring) + 4-phase decomposition -----------
#define FENCE_BAR                                             \
    asm volatile("s_waitcnt lgkmcnt(0)" ::: "memory");        \
    __builtin_amdgcn_s_barrier();                             \
    asm volatile("" ::: "memory");

__global__ __launch_bounds__(512, 1)
void k2_scan(const int* __restrict__ lengths, const float* __restrict__ wsW2,
             const float* __restrict__ xp,
             float* __restrict__ stH, float* __restrict__ stC, float* __restrict__ lastH,
             int t0, int t1, int tcAlloc)
{
    const int b = blockIdx.x, tid = threadIdx.x;
    // hT[buf][p][36]: hT[.][p][m] = h[4m+p]; 36-pad -> phase rows start on banks 0/4/8/12
    __shared__ __align__(16) float hT[2][4][36];
    __shared__ __align__(16) float ring[4][256];    // xp ring, 4 steps deep

    const bool gm   = tid < 400;               // compute lanes
    const bool st   = tid >= 448;              // stager wave (wave 7; 400-447 idle)
    const int  k    = tid >> 3;                // hidden unit
    const int  h_   = (tid >> 2) & 1;          // gate pair: 0=(i,f) 1=(g,o)
    const int  p    = tid & 3;                 // K-phase (j == p mod 4)
    const bool isp0 = (p == 0);
    const bool h1v  = (h_ == 1);
    const bool wlead = gm && ((tid & 7) == 0);
    const int  nsteps = t1 - t0;

    // ---- phase A: compiler-visible loads + LDS init ----
    int lastidx = min(lengths[b], NT) - 1;
    float cst = 0.f, hinit = 0.f;
    if (gm && t0 != 0) cst = stC[b * NH + k];
    if (tid < NH && t0 != 0) hinit = stH[b * NH + tid];
    if (tid < 288) ((float*)hT)[tid] = 0.f;    // zero both buffers incl. pads
    __syncthreads();
    if (tid < NH) hT[0][tid & 3][tid >> 2] = hinit;   // h[j] -> [j%4][j/4]

    // ---- phase B: weights (26 floats/lane, asm-pinned) ----
    f32x4 A0{}, A1{}, A2{}, A3{}, A4{}, A5{};
    f32x2 T{};
    float sce = 1.f, ade = 0.f, hkeep = 0.f, hfin = 0.f;
    if (gm) {
        const float* wr_ = wsW2 + tid * 28;
        gload4(A0, wr_ + 0);  gload4(A1, wr_ + 4);  gload4(A2, wr_ + 8);
        gload4(A3, wr_ + 12); gload4(A4, wr_ + 16); gload4(A5, wr_ + 20);
        gload2(T, wr_ + 24);
        asm volatile("s_waitcnt vmcnt(0)" ::: "memory");
        __builtin_amdgcn_sched_barrier(0);
        if (h1v) { sce = 2.f; ade = -1.f; }    // even gate of pair 1 is g: tanh via sigmoid
    }
    // ---- stager prologue (R5-proven): 4-deep, slot 0 published before first barrier ----
    const float* xpb = xp + (size_t)b * tcAlloc * 200;
    const int sl = tid - 448;
    f32x4 p1{}, p2{}, p3{};
    if (st) {
        f32x4 q0 = *(const f32x4*)(xpb + 0 * 200 + 4 * sl);
        p1 = *(const f32x4*)(xpb + 1 * 200 + 4 * sl);
        p2 = *(const f32x4*)(xpb + 2 * 200 + 4 * sl);
        p3 = *(const f32x4*)(xpb + 3 * 200 + 4 * sl);
        *(f32x4*)&ring[0][4 * sl] = q0;
    }
    FENCE_BAR

    // ---- main loop: compute waves have ZERO VMEM; 5 LDS ops + 2 swizzles per lane -------
    for (int s = 0; s < nsteps; ++s) {
        if (gm) {
            const int cur = s & 1;
            const float* hp = &hT[cur][p][0];
            const f32x4* hq = (const f32x4*)hp;
            f32x4 h0 = hq[0], h1 = hq[1], h2 = hq[2];      // h[4m+p], m=0..11
            float htl = hT[cur][p ^ 2][12];                 // p2->h48, p3->h49, p0/p1->0
            f32x2 xq = *(const f32x2*)&ring[s & 3][(k << 2) | (h_ << 1)];
            float ae = isp0 ? xq.x : 0.f;                   // seed on phase-0 lane only
            float ao = isp0 ? xq.y : 0.f;
            ae = fmaf(h0.x, A0.x, ae); ao = fmaf(h0.x, A0.y, ao);
            ae = fmaf(h0.y, A0.z, ae); ao = fmaf(h0.y, A0.w, ao);
            ae = fmaf(h0.z, A1.x, ae); ao = fmaf(h0.z, A1.y, ao);
            ae = fmaf(h0.w, A1.z, ae); ao = fmaf(h0.w, A1.w, ao);
            ae = fmaf(h1.x, A2.x, ae); ao = fmaf(h1.x, A2.y, ao);
            ae = fmaf(h1.y, A2.z, ae); ao = fmaf(h1.y, A2.w, ao);
            ae = fmaf(h1.z, A3.x, ae); ao = fmaf(h1.z, A3.y, ao);
            ae = fmaf(h1.w, A3.z, ae); ao = fmaf(h1.w, A3.w, ao);
            ae = fmaf(h2.x, A4.x, ae); ao = fmaf(h2.x, A4.y, ao);
            ae = fmaf(h2.y, A4.z, ae); ao = fmaf(h2.y, A4.w, ao);
            ae = fmaf(h2.z, A5.x, ae); ao = fmaf(h2.z, A5.y, ao);
            ae = fmaf(h2.w, A5.z, ae); ao = fmaf(h2.w, A5.w, ao);
            ae = fmaf(htl, T.x, ae);   ao = fmaf(htl, T.y, ao);   // tails append to a2/a3 chains
            // phase recombine via DPP: bitwise (a0+a1)+(a2+a3) (commutativity only)
            float te = ae + qp<0xB1>(ae); te = te + qp<0x4E>(te);
            float to = ao + qp<0xB1>(ao); to = to + qp<0x4E>(to);
            float acte = fmaf(rcpf(1.f + __expf(-sce * te)), sce, ade);
            float acto = rcpf(1.f + __expf(-to));
            // gate-pair exchange across h_ (xor4)
            float oe = swz4(acte), oo = swz4(acto);
            float i_ = h1v ? oe : acte;
            float f_ = h1v ? oo : acto;
            float g_ = h1v ? acte : oe;
            float o_ = h1v ? acto : oo;
            cst = fmaf(f_, cst, i_ * g_);
            float th = fmaf(rcpf(1.f + __expf(-2.f * cst)), 2.f, -1.f);
            float hv = o_ * th;
            if (wlead) hT[cur ^ 1][k & 3][k >> 2] = hv;
            hfin = hv;
            hkeep = (t0 + s == lastidx) ? hv : hkeep;
        }
        if (st) {
            *(f32x4*)&ring[(s + 1) & 3][4 * sl] = p1;                         // publish t=s+1
            f32x4 pn = *(const f32x4*)(xpb + (size_t)(s + 4) * 200 + 4 * sl); // fetch t=s+4
            p1 = p2; p2 = p3; p3 = pn;
        }
        FENCE_BAR
    }

    if (wlead) {
        stH[b * NH + k] = hfin;
        stC[b * NH + k] = cst;
        if (lastidx >= t0 && lastidx < t1) lastH[b * NH + k] = hkeep;
    }
}

// ---------------- K3: pooling + concat + linear (unchanged — proven) ---------------------
__global__ __launch_bounds__(256)
void k3_final(const int* __restrict__ x, const int* __restrict__ lengths,
              const float* __restrict__ emb_table,
              const float* __restrict__ W_lin, const float* __restrict__ b_lin,
              const float* __restrict__ lastH, float* __restrict__ out)
{
    const int b = blockIdx.x, tid = threadIdx.x;
    __shared__ int xv[NT];
    __shared__ float ps[5][52], pm[5][52];
    __shared__ float rep[160];

    for (int i = tid; i < NT; i += 256) xv[i] = x[(size_t)b * NT + i];
    __syncthreads();
    const int g = tid / ND, d = tid - g * ND;
    if (tid < 250) {
        float s = 0.f, m = -INFINITY;
        #pragma unroll 4
        for (int t = g; t < NT; t += 5) {
            float e = emb_table[(size_t)xv[t] * ND + d];
            s += e; m = fmaxf(m, e);
        }
        ps[g][d] = s; pm[g][d] = m;
    }
    __syncthreads();
    if (tid < NH) {
        float s = ps[0][tid] + ps[1][tid] + ps[2][tid] + ps[3][tid] + ps[4][tid];
        float m = fmaxf(fmaxf(fmaxf(pm[0][tid], pm[1][tid]), fmaxf(pm[2][tid], pm[3][tid])), pm[4][tid]);
        rep[tid]          = lastH[b * NH + tid];
        rep[NH + tid]     = s / (float)lengths[b];
        rep[2 * NH + tid] = m;
    }
    __syncthreads();
    if (tid < NC) {
        float acc = b_lin[tid];
        #pragma unroll 5
        for (int j = 0; j < 3 * NH; ++j)
            acc = fmaf(rep[j], W_lin[tid * 3 * NH + j], acc);
        out[(size_t)b * NC + tid] = acc;
    }
}

extern "C" void kernel_launch(void* const* d_in, const int* in_sizes, int n_in,
                              void* d_out, int out_size, void* d_ws, size_t ws_size,
                              hipStream_t stream) {
    const int*   x     = (const int*)d_in[0];
    const int*   len   = (const int*)d_in[1];
    const float* emb   = (const float*)d_in[3];
    const float* W_ih  = (const float*)d_in[4];
    const float* W_hh  = (const float*)d_in[5];
    const float* b_ih  = (const float*)d_in[6];
    const float* b_hh  = (const float*)d_in[7];
    const float* W_lin = (const float*)d_in[8];
    const float* b_lin = (const float*)d_in[9];
    float* outp = (float*)d_out;

    // ws: [stH][stC][lastH] | @160KB: wsWih[200*52], wsW2[400*28] | @256KB: xp (+8KB slack)
    float* stH   = (float*)d_ws;
    float* stC   = stH + NB * NH;
    float* lastH = stC + NB * NH;
    float* wsWih = (float*)((char*)d_ws + 160 * 1024);
    float* wsW2  = wsWih + 200 * 52;
    const size_t xpOff = 256 * 1024;
    float* xp = (float*)((char*)d_ws + xpOff);

    size_t avail = (ws_size > xpOff + 8192) ? ws_size - xpOff - 8192 : 0;
    int tc = (int)(avail / ((size_t)NB * 200 * sizeof(float)));
    tc &= ~3;
    if (tc > NT) tc = NT;
    if (tc < 4)  tc = 4;

    hipLaunchKernelGGL(k0_prep, dim3(85), dim3(256), 0, stream, W_hh, W_ih, wsWih, wsW2);

    for (int t0 = 0; t0 < NT; t0 += tc) {
        const int t1 = min(NT, t0 + tc);
        const int tiles = (t1 - t0 + 63) / 64;
        hipLaunchKernelGGL(k1_xproj, dim3(NB * tiles), dim3(256), 0, stream,
                           x, len, emb, wsWih, b_ih, b_hh, xp, t0, t1, tiles, tc);
        hipLaunchKernelGGL(k2_scan, dim3(NB), dim3(512), 0, stream,
                           len, wsW2, xp, stH, stC, lastH, t0, t1, tc);
    }
    hipLaunchKernelGGL(k3_final, dim3(NB), dim3(256), 0, stream,
                       x, len, emb, W_lin, b_lin, lastH, outp);
}